// Round 18
// baseline (84.346 us; speedup 1.0000x reference)
//
#include <hip/hip_runtime.h>
#include <hip/hip_bf16.h>
#include <math.h>

// B=8192, D=1024, H=128, C=16
// out tuple: masked[B*D], mask_norm(0.0), embed_norm(||x||F), x[B*D] -> f32
#define B_ 8192
#define D_ 1024
#define H_ 128
#define C_ 16
#define BD (B_*D_)
#define SUBR 16             // rows per subtile (padded per cond)
#define SLOTS 68            // MLP slots per XCD; MLP grid = 8*68 = 544
#define MAXSUB 150
#define GRID_MLP 544
#define GRID_COPY 512
#define GRID_F (GRID_MLP + GRID_COPY)

using bf16x8 = __attribute__((ext_vector_type(8))) __bf16;
using f32x4  = __attribute__((ext_vector_type(4))) float;
typedef unsigned short ushort_t;

// ws layout (bytes):
//   int 16      : nsub[8]
//   int 24      : done counter (copy blocks)
//   int 32      : subtbl[8][150][3] (cond, prow0, end)
//   int 8192    : sidx[8448]  padded sorted-pos -> orig row  (byte 32768)
//   131072      : xpart[512] f32 (per-copy-block ||x||^2 partials)
//   262144      : w1s bf16 (4 MiB)  [cond][jf8][ks32][lane64][8]
//   4456448     : w2s bf16 (4 MiB)  [cond][jf64][ks4][lane64][8]

__device__ inline bf16x8 cvt8(float4 a, float4 b) {
    bf16x8 r;
    r[0] = (__bf16)a.x; r[1] = (__bf16)a.y; r[2] = (__bf16)a.z; r[3] = (__bf16)a.w;
    r[4] = (__bf16)b.x; r[5] = (__bf16)b.y; r[6] = (__bf16)b.z; r[7] = (__bf16)b.w;
    return r;
}
__device__ inline unsigned pack2(float a, float b) {
    unsigned ua = __builtin_bit_cast(unsigned short, (__bf16)a);
    unsigned ub = __builtin_bit_cast(unsigned short, (__bf16)b);
    return ua | (ub << 16);
}

// ---- prep: 0..127 W1 (LDS transpose), 128..255 W2, 256 sort ----
__global__ __launch_bounds__(256) void k_prep(const float* __restrict__ W1f,
                                              const float* __restrict__ W2f,
                                              const int* __restrict__ c,
                                              __bf16* __restrict__ w1s,
                                              __bf16* __restrict__ w2s,
                                              int* __restrict__ w) {
    __shared__ ulong2 stg[2048];            // 32 KB permute buffer
    bf16x8* stgv = (bf16x8*)stg;
    int bid = blockIdx.x, tid = threadIdx.x;

    if (bid < 128) {                        // W1: coalesced read -> LDS permute -> coalesced write
        size_t mbase = (size_t)bid * 2048;  // block-closed permutation
#pragma unroll
        for (int u = 0; u < 8; ++u) {
            int ml = u * 256 + tid;         // row=ml>>7 (16 rows), cc8=ml&127
            const float* src = W1f + (mbase + ml) * 8;
            float4 f0 = *(const float4*)src, f1 = *(const float4*)(src + 4);
            int row = ml >> 7, cc8 = ml & 127;
            stgv[row * 128 + (cc8 ^ (row & 7))] = cvt8(f0, f1);
        }
        __syncthreads();
#pragma unroll
        for (int u = 0; u < 8; ++u) {
            int o = u * 256 + tid;          // ks=o>>6, kg=(o>>4)&3, l15=o&15
            int ks = o >> 6, kg = (o >> 4) & 3, l15 = o & 15;
            bf16x8 v = stgv[l15 * 128 + ((ks * 4 + kg) ^ (l15 & 7))];
            *(bf16x8*)(w1s + (mbase + o) * 8) = v;
        }
    } else if (bid < 256) {                 // W2: same block-closed LDS transpose
        int b = bid - 128;
        size_t mbase = (size_t)b * 2048;
#pragma unroll
        for (int u = 0; u < 8; ++u) {
            int ml = u * 256 + tid;         // row_rel=ml>>4 (128 rows), cc8=ml&15
            const float* src = W2f + (mbase + ml) * 8;
            float4 f0 = *(const float4*)src, f1 = *(const float4*)(src + 4);
            int rr = ml >> 4, cc8 = ml & 15;
            stgv[rr * 16 + (cc8 ^ (rr & 15))] = cvt8(f0, f1);
        }
        __syncthreads();
#pragma unroll
        for (int u = 0; u < 8; ++u) {
            int o = u * 256 + tid;          // jf_rel=o>>8, ks=(o>>6)&3, kg=(o>>4)&3, l15=o&15
            int jfr = o >> 8, ks = (o >> 6) & 3, kg = (o >> 4) & 3, l15 = o & 15;
            int rr = jfr * 16 + l15, cc8 = ks * 4 + kg;
            bf16x8 v = stgv[rr * 16 + (cc8 ^ (rr & 15))];
            *(bf16x8*)(w2s + (mbase + o) * 8) = v;
        }
    } else {                                // sort: hist + padded table + scatter; zero counter
        __shared__ int hist[C_], base[C_], poff[C_], nt[C_];
        if (tid < C_) hist[tid] = 0;
        if (tid == 0) w[24] = 0;            // done counter
        __syncthreads();
        for (int i = tid; i < B_; i += 256) atomicAdd(&hist[c[i]], 1);
        __syncthreads();
        if (tid == 0) {
            int off = 0;
            for (int cc = 0; cc < C_; ++cc) {
                nt[cc] = (hist[cc] + SUBR - 1) >> 4;
                poff[cc] = off;
                base[cc] = off;
                off += nt[cc] * SUBR;       // padded to 16-row alignment
            }
        }
        __syncthreads();
        if (tid < C_) {                     // per-cond parallel table build
            int cc = tid, xcd = cc >> 1;
            int s0 = (cc & 1) ? nt[cc - 1] : 0;
            int end = poff[cc] + hist[cc];
            for (int t = 0; t < nt[cc]; ++t) {
                int* e = &w[32 + (xcd * MAXSUB + s0 + t) * 3];
                e[0] = cc; e[1] = poff[cc] + t * SUBR; e[2] = end;
            }
            if ((cc & 1) == 0) w[16 + xcd] = nt[cc] + nt[cc + 1];
        }
        __syncthreads();
        for (int i = tid; i < B_; i += 256) {
            int pos = atomicAdd(&base[c[i]], 1);
            w[8192 + pos] = i;              // sidx (padded positions)
        }
    }
}

// ---- k_f: 544 MLP blocks + 512 independent x-copy blocks (overlap BW with latency) ----
__global__ __launch_bounds__(512, 4) void k_f(const float* __restrict__ x,
                                              const __bf16* __restrict__ w1s,
                                              const __bf16* __restrict__ w2s,
                                              const float* __restrict__ b1f,
                                              const float* __restrict__ b2f,
                                              int* __restrict__ wsi,
                                              float* __restrict__ xpart,
                                              float* __restrict__ out) {
    __shared__ ulong2 xot_raw[2048];        // 32 KB: x frags -> bf16 out-tile
    __shared__ ushort_t Hs[16 * 128];       // 4 KB h tile (slot-XOR swizzled)
    __shared__ float sqs[16 * 8];
    __shared__ int lastFlag;
    char* ldsx = (char*)xot_raw;
    unsigned* Ot32 = (unsigned*)xot_raw;    // [rowpair8][col1024] u32 = rows (2r,2r+1)

    int tid = threadIdx.x, wv = tid >> 6, lane = tid & 63, l15 = lane & 15, kg = lane >> 4;

    if (blockIdx.x >= GRID_MLP) {
        // ======== x-copy block: xcopy + ||x||^2; pure stream, no barriers w/ MLP ========
        int cb = blockIdx.x - GRID_MLP;     // 0..511
        size_t base0 = (size_t)cb * 16384;  // floats
        float xsq = 0.0f;
#pragma unroll
        for (int u = 0; u < 8; ++u) {
            size_t idx = base0 + u * 2048 + tid * 4;
            float4 f = *(const float4*)(x + idx);
            float2* xo = (float2*)(out + (size_t)BD + 2 + idx);
            xo[0] = make_float2(f.x, f.y);
            xo[1] = make_float2(f.z, f.w);
            xsq += f.x*f.x + f.y*f.y + f.z*f.z + f.w*f.w;
        }
        float s = xsq;
        s += __shfl_xor(s, 1);  s += __shfl_xor(s, 2);  s += __shfl_xor(s, 4);
        s += __shfl_xor(s, 8);  s += __shfl_xor(s, 16); s += __shfl_xor(s, 32);
        if (lane == 0) sqs[wv] = s;
        __syncthreads();
        if (tid == 0) {
            xpart[cb] = sqs[0] + sqs[1] + sqs[2] + sqs[3] + sqs[4] + sqs[5] + sqs[6] + sqs[7];
            __threadfence();
            int prev = atomicAdd(&wsi[24], 1);
            lastFlag = (prev == GRID_COPY - 1);
        }
        __syncthreads();
        if (lastFlag) {                     // last copy block finalizes the two scalars
            __threadfence();
            float v = xpart[tid];           // 512 threads, 512 partials
            v += __shfl_xor(v, 1);  v += __shfl_xor(v, 2);  v += __shfl_xor(v, 4);
            v += __shfl_xor(v, 8);  v += __shfl_xor(v, 16); v += __shfl_xor(v, 32);
            if (lane == 0) sqs[wv] = v;
            __syncthreads();
            if (tid == 0) {
                float e = sqs[0] + sqs[1] + sqs[2] + sqs[3] + sqs[4] + sqs[5] + sqs[6] + sqs[7];
                out[BD] = 0.0f;
                out[BD + 1] = sqrtf(e);
            }
        }
        return;
    }

    // ======== MLP block ========
    int xcd = blockIdx.x & 7, slot0 = blockIdx.x >> 3;
    int nsub = wsi[16 + xcd];
    const int* sidx = wsi + 8192;

    int sr = wv * 2 + (lane >> 5);          // staging row: wave covers rows 2wv,2wv+1
    int cg = lane & 31;                     // 32 lanes cover a row contiguously
    int skg = cg & 3, skb = cg >> 2;

    for (int si = slot0; si < nsub; si += SLOTS) {
        const int* e = wsi + 32 + (xcd * MAXSUB + si) * 3;
        int cond = e[0], prow0 = e[1], end = e[2];

        // ---- stage x: gather 16 f32 rows (4KB contiguous each), cvt -> fragment LDS ----
        {
            int pr = prow0 + sr;
            int orow = sidx[pr < end ? pr : (end - 1)];
            const float* xs = x + (size_t)orow * D_;
#pragma unroll
            for (int it = 0; it < 4; ++it) {
                int col0 = it * 256 + cg * 8;
                float4 f0 = *(const float4*)(xs + col0);
                float4 f1 = *(const float4*)(xs + col0 + 4);
                int ks = it * 8 + skb;
                *(bf16x8*)(ldsx + ks * 1024 + skg * 256 + ((sr ^ skb) * 16)) = cvt8(f0, f1);
            }
        }
        __syncthreads();

        // ---- L1: wave wv computes h cols [wv*16,+16); batched weight loads ----
        const char* bA = (const char*)w1s + (size_t)cond * 262144 + wv * 32768 + lane * 16;
        f32x4 acc = {};
#pragma unroll 1
        for (int kb = 0; kb < 4; ++kb) {
            bf16x8 b0 = *(const bf16x8*)(bA + (kb * 8 + 0) * 1024);
            bf16x8 b1 = *(const bf16x8*)(bA + (kb * 8 + 1) * 1024);
            bf16x8 b2 = *(const bf16x8*)(bA + (kb * 8 + 2) * 1024);
            bf16x8 b3 = *(const bf16x8*)(bA + (kb * 8 + 3) * 1024);
            bf16x8 b4 = *(const bf16x8*)(bA + (kb * 8 + 4) * 1024);
            bf16x8 b5 = *(const bf16x8*)(bA + (kb * 8 + 5) * 1024);
            bf16x8 b6 = *(const bf16x8*)(bA + (kb * 8 + 6) * 1024);
            bf16x8 b7 = *(const bf16x8*)(bA + (kb * 8 + 7) * 1024);
#pragma unroll
            for (int j = 0; j < 8; ++j) {
                int ks = kb * 8 + j;
                bf16x8 x0 = *(const bf16x8*)(ldsx + ks * 1024 + kg * 256 + ((l15 ^ (ks & 7)) * 16));
                bf16x8 bj = j == 0 ? b0 : j == 1 ? b1 : j == 2 ? b2 : j == 3 ? b3
                          : j == 4 ? b4 : j == 5 ? b5 : j == 6 ? b6 : b7;
                acc = __builtin_amdgcn_mfma_f32_16x16x32_bf16(x0, bj, acc, 0, 0, 0);
            }
        }
        __syncthreads();   // all waves done reading x region

        // ---- h + b1 -> Hs (swizzled bf16) ----
        {
            int j0 = wv * 16 + l15;
            float bias = b1f[cond * 128 + j0];
            int sl0 = j0 >> 3, jb = j0 & 7;
#pragma unroll
            for (int v = 0; v < 4; ++v) {
                int r0 = kg * 4 + v;
                __bf16 h0 = (__bf16)(acc[v] + bias);
                Hs[r0 * 128 + ((sl0 ^ (r0 & 7)) * 8) + jb] = __builtin_bit_cast(ushort_t, h0);
            }
        }
        __syncthreads();

        // ---- pa fragments ----
        bf16x8 pa[4];
#pragma unroll
        for (int i = 0; i < 4; ++i)
            pa[i] = *(const bf16x8*)(Hs + l15 * 128 + (((i * 4 + kg) ^ (l15 & 7)) * 8));

        // ---- L2: wave wv owns out cols [wv*128,+128) ----
        const char* w2b = (const char*)w2s + (size_t)cond * 262144 + wv * 32768 + lane * 16;
        float sq[4] = {0.f, 0.f, 0.f, 0.f};
        unsigned cswz = (unsigned)((kg & 1) << 4);
#pragma unroll 1
        for (int f = 0; f < 8; ++f) {
            const char* wb = w2b + f * 4096;
            bf16x8 q0 = *(const bf16x8*)(wb);
            bf16x8 q1 = *(const bf16x8*)(wb + 1024);
            bf16x8 q2 = *(const bf16x8*)(wb + 2048);
            bf16x8 q3 = *(const bf16x8*)(wb + 3072);
            f32x4 c0 = {};
            c0 = __builtin_amdgcn_mfma_f32_16x16x32_bf16(pa[0], q0, c0, 0, 0, 0);
            c0 = __builtin_amdgcn_mfma_f32_16x16x32_bf16(pa[1], q1, c0, 0, 0, 0);
            c0 = __builtin_amdgcn_mfma_f32_16x16x32_bf16(pa[2], q2, c0, 0, 0, 0);
            c0 = __builtin_amdgcn_mfma_f32_16x16x32_bf16(pa[3], q3, c0, 0, 0, 0);
            int jg = (wv * 8 + f) * 16 + l15;
            float bias = b2f[cond * 1024 + jg];
            float t0 = c0[0] + bias, t1 = c0[1] + bias, t2 = c0[2] + bias, t3 = c0[3] + bias;
            sq[0] += t0*t0; sq[1] += t1*t1; sq[2] += t2*t2; sq[3] += t3*t3;
            unsigned jc = (unsigned)jg ^ cswz;
            Ot32[(kg * 2    ) * 1024 + jc] = pack2(t0, t1);
            Ot32[(kg * 2 + 1) * 1024 + jc] = pack2(t2, t3);
        }
        // per-row sums: shfl over l15 -> LDS across waves
#pragma unroll
        for (int v = 0; v < 4; ++v) {
            float s = sq[v];
            s += __shfl_xor(s, 1); s += __shfl_xor(s, 2);
            s += __shfl_xor(s, 4); s += __shfl_xor(s, 8);
            if (l15 == 0) sqs[(kg * 4 + v) * 8 + wv] = s;
        }
        __syncthreads();

        // ---- fused normalize + fully-coalesced store: wave wv -> rows [wv*2,+2) ----
#pragma unroll 1
        for (int rr = 0; rr < 2; ++rr) {
            int r = wv * 2 + rr;
            int pr = prow0 + r;
            if (pr < end) {
                int orow = sidx[pr];
                float s = sqs[r*8+0] + sqs[r*8+1] + sqs[r*8+2] + sqs[r*8+3]
                        + sqs[r*8+4] + sqs[r*8+5] + sqs[r*8+6] + sqs[r*8+7];
                float inv = 1.0f / (sqrtf(s) + 1e-10f);
                int hi = (r & 1) * 16;
                unsigned rswz = (unsigned)(((r >> 2) & 1) << 4);
                const unsigned* base = Ot32 + (r >> 1) * 1024;
                float4* go = (float4*)(out + (size_t)orow * D_);
#pragma unroll
                for (int it = 0; it < 4; ++it) {
                    unsigned cu = (unsigned)(lane * 4 + it * 256) ^ rswz;
                    uint4 u = *(const uint4*)(base + cu);
                    float4 v;
                    v.x = (float)__builtin_bit_cast(__bf16, (ushort_t)(u.x >> hi)) * inv;
                    v.y = (float)__builtin_bit_cast(__bf16, (ushort_t)(u.y >> hi)) * inv;
                    v.z = (float)__builtin_bit_cast(__bf16, (ushort_t)(u.z >> hi)) * inv;
                    v.w = (float)__builtin_bit_cast(__bf16, (ushort_t)(u.w >> hi)) * inv;
                    go[lane + it * 64] = v;
                }
            }
        }
        __syncthreads();   // protect LDS for next subtile
    }
}

extern "C" void kernel_launch(void* const* d_in, const int* in_sizes, int n_in,
                              void* d_out, int out_size, void* d_ws, size_t ws_size,
                              hipStream_t stream) {
    const float* x  = (const float*)d_in[0];
    const int*   c  = (const int*)d_in[1];
    const float* W1 = (const float*)d_in[2];
    const float* b1 = (const float*)d_in[3];
    const float* W2 = (const float*)d_in[4];
    const float* b2 = (const float*)d_in[5];
    float* out = (float*)d_out;
    char* ws = (char*)d_ws;
    int* wsi = (int*)ws;
    float* xpart = (float*)(ws + 131072);
    __bf16* w1s  = (__bf16*)(ws + 262144);
    __bf16* w2s  = (__bf16*)(ws + 4456448);

    k_prep<<<257, 256, 0, stream>>>(W1, W2, c, w1s, w2s, wsi);
    k_f<<<GRID_F, 512, 0, stream>>>(x, w1s, w2s, b1, b2, wsi, xpart, out);
}

// Round 20
// 63.807 us; speedup vs baseline: 1.3219x; 1.3219x over previous
//
#include <hip/hip_runtime.h>
#include <hip/hip_bf16.h>
#include <math.h>

// B=8192, D=1024, H=128, C=16
// out tuple: masked[B*D], mask_norm(0.0), embed_norm(||x||F), x[B*D] -> f32
#define B_ 8192
#define D_ 1024
#define H_ 128
#define C_ 16
#define BD (B_*D_)
#define SUBR 16             // rows per subtile (padded per cond)
#define SLOTS 68            // slots per XCD; grid = 8*68 = 544
#define MAXSUB 150
#define GRID_F (8 * SLOTS)

using bf16x8 = __attribute__((ext_vector_type(8))) __bf16;
using f32x4  = __attribute__((ext_vector_type(4))) float;
using f32x2  = __attribute__((ext_vector_type(2))) float;   // native vector for nt stores
typedef unsigned short ushort_t;

// ws layout (bytes):
//   int 16      : nsub[8]
//   int 32      : subtbl[8][150][3] (cond, prow0, end)
//   int 8192    : sidx[8448]  padded sorted-pos -> orig row  (byte 32768)
//   131072      : xpart[2048] f32 (per-stream-block ||x||^2 partials)
//   262144      : w1s bf16 (4 MiB)  [cond][jf8][ks32][lane64][8]
//   4456448     : w2s bf16 (4 MiB)  [cond][jf64][ks4][lane64][8]
//   8650752     : xbf bf16[8192][1024] (16 MiB, original row order)

__device__ inline bf16x8 cvt8(float4 a, float4 b) {
    bf16x8 r;
    r[0] = (__bf16)a.x; r[1] = (__bf16)a.y; r[2] = (__bf16)a.z; r[3] = (__bf16)a.w;
    r[4] = (__bf16)b.x; r[5] = (__bf16)b.y; r[6] = (__bf16)b.z; r[7] = (__bf16)b.w;
    return r;
}
__device__ inline unsigned pack2(float a, float b) {
    unsigned ua = __builtin_bit_cast(unsigned short, (__bf16)a);
    unsigned ub = __builtin_bit_cast(unsigned short, (__bf16)b);
    return ua | (ub << 16);
}

// ---- prep: 0..127 W1 (LDS transpose), 128..255 W2, 256 sort, 257..2304 x-stream ----
__global__ __launch_bounds__(256) void k_prep(const float* __restrict__ W1f,
                                              const float* __restrict__ W2f,
                                              const int* __restrict__ c,
                                              const float* __restrict__ x,
                                              __bf16* __restrict__ w1s,
                                              __bf16* __restrict__ w2s,
                                              __bf16* __restrict__ xbf,
                                              int* __restrict__ w,
                                              float* __restrict__ xpart,
                                              float* __restrict__ out) {
    __shared__ ulong2 stg[2048];            // 32 KB permute buffer (weight blocks)
    bf16x8* stgv = (bf16x8*)stg;
    int bid = blockIdx.x, tid = threadIdx.x;

    if (bid < 128) {                        // W1: coalesced read -> LDS permute -> coalesced write
        size_t mbase = (size_t)bid * 2048;  // 16B-chunk base (block-closed permutation)
#pragma unroll
        for (int u = 0; u < 8; ++u) {
            int ml = u * 256 + tid;         // local chunk: row=ml>>7 (16 rows), cc8=ml&127
            const float* src = W1f + (mbase + ml) * 8;
            float4 f0 = *(const float4*)src, f1 = *(const float4*)(src + 4);
            int row = ml >> 7, cc8 = ml & 127;
            stgv[row * 128 + (cc8 ^ (row & 7))] = cvt8(f0, f1);
        }
        __syncthreads();
#pragma unroll
        for (int u = 0; u < 8; ++u) {
            int o = u * 256 + tid;          // dest chunk: ks=o>>6, kg=(o>>4)&3, l15=o&15
            int ks = o >> 6, kg = (o >> 4) & 3, l15 = o & 15;
            bf16x8 v = stgv[l15 * 128 + ((ks * 4 + kg) ^ (l15 & 7))];
            *(bf16x8*)(w1s + (mbase + o) * 8) = v;
        }
    } else if (bid < 256) {                 // W2: same block-closed LDS transpose
        int b = bid - 128;
        size_t mbase = (size_t)b * 2048;
#pragma unroll
        for (int u = 0; u < 8; ++u) {
            int ml = u * 256 + tid;         // row_rel=ml>>4 (128 rows), cc8=ml&15
            const float* src = W2f + (mbase + ml) * 8;
            float4 f0 = *(const float4*)src, f1 = *(const float4*)(src + 4);
            int rr = ml >> 4, cc8 = ml & 15;
            stgv[rr * 16 + (cc8 ^ (rr & 15))] = cvt8(f0, f1);
        }
        __syncthreads();
#pragma unroll
        for (int u = 0; u < 8; ++u) {
            int o = u * 256 + tid;          // jf_rel=o>>8, ks=(o>>6)&3, kg=(o>>4)&3, l15=o&15
            int jfr = o >> 8, ks = (o >> 6) & 3, kg = (o >> 4) & 3, l15 = o & 15;
            int rr = jfr * 16 + l15, cc8 = ks * 4 + kg;
            bf16x8 v = stgv[rr * 16 + (cc8 ^ (rr & 15))];
            *(bf16x8*)(w2s + (mbase + o) * 8) = v;
        }
    } else if (bid == 256) {                // sort: hist + padded table + scatter
        __shared__ int hist[C_], base[C_], poff[C_], nt[C_];
        if (tid < C_) hist[tid] = 0;
        __syncthreads();
        for (int i = tid; i < B_; i += 256) atomicAdd(&hist[c[i]], 1);
        __syncthreads();
        if (tid == 0) {
            int off = 0;
            for (int cc = 0; cc < C_; ++cc) {
                nt[cc] = (hist[cc] + SUBR - 1) >> 4;
                poff[cc] = off;
                base[cc] = off;
                off += nt[cc] * SUBR;       // padded to 16-row alignment
            }
        }
        __syncthreads();
        if (tid < C_) {                     // per-cond parallel table build
            int cc = tid, xcd = cc >> 1;
            int s0 = (cc & 1) ? nt[cc - 1] : 0;
            int end = poff[cc] + hist[cc];
            for (int t = 0; t < nt[cc]; ++t) {
                int* e = &w[32 + (xcd * MAXSUB + s0 + t) * 3];
                e[0] = cc; e[1] = poff[cc] + t * SUBR; e[2] = end;
            }
            if ((cc & 1) == 0) w[16 + xcd] = nt[cc] + nt[cc + 1];
        }
        __syncthreads();
        for (int i = tid; i < B_; i += 256) {
            int pos = atomicAdd(&base[c[i]], 1);
            w[8192 + pos] = i;              // sidx (padded positions)
        }
    } else {                                // x-stream: 4 rows/block, 2048 blocks; nt xcopy
        int xb = bid - 257;                 // 0..2047
        size_t base0 = (size_t)xb * 4096;
        float xsq = 0.0f;
#pragma unroll
        for (int u = 0; u < 4; ++u) {
            size_t idx = base0 + u * 1024 + tid * 4;   // lane owns 4 consecutive floats
            float4 f = *(const float4*)(x + idx);
            *(uint2*)(xbf + idx) = make_uint2(pack2(f.x, f.y), pack2(f.z, f.w));
            f32x2* xo = (f32x2*)(out + (size_t)BD + 2 + idx);
            f32x2 lo, hi;
            lo[0] = f.x; lo[1] = f.y; hi[0] = f.z; hi[1] = f.w;
            __builtin_nontemporal_store(lo, xo);        // write-once stream
            __builtin_nontemporal_store(hi, xo + 1);
            xsq += f.x*f.x + f.y*f.y + f.z*f.z + f.w*f.w;
        }
        float s = xsq;
        s += __shfl_xor(s, 1);  s += __shfl_xor(s, 2);  s += __shfl_xor(s, 4);
        s += __shfl_xor(s, 8);  s += __shfl_xor(s, 16); s += __shfl_xor(s, 32);
        __shared__ float red[4];
        int lane = tid & 63, wv = tid >> 6;
        if (lane == 0) red[wv] = s;
        __syncthreads();
        if (tid == 0) xpart[xb] = red[0] + red[1] + red[2] + red[3];
    }
}

// ---- k_f: stage from xbf + MLP + normalize; last block computes scalars ----
__global__ __launch_bounds__(512, 4) void k_f(const __bf16* __restrict__ xbf,
                                              const __bf16* __restrict__ w1s,
                                              const __bf16* __restrict__ w2s,
                                              const float* __restrict__ b1f,
                                              const float* __restrict__ b2f,
                                              const int* __restrict__ wsi,
                                              const float* __restrict__ xpart,
                                              float* __restrict__ out) {
    int xcd = blockIdx.x & 7, slot0 = blockIdx.x >> 3;
    int nsub = wsi[16 + xcd];
    const int* sidx = wsi + 8192;

    __shared__ ulong2 xot_raw[2048];        // 32 KB: x frags -> bf16 out-tile
    __shared__ ushort_t Hs[16 * 128];       // 4 KB h tile (slot-XOR swizzled)
    __shared__ float sqs[16 * 8];
    char* ldsx = (char*)xot_raw;
    unsigned* Ot32 = (unsigned*)xot_raw;    // [rowpair8][col1024] u32 = rows (2r,2r+1)

    int tid = threadIdx.x, wv = tid >> 6, lane = tid & 63, l15 = lane & 15, kg = lane >> 4;
    int sr = wv * 2 + (lane >> 5);          // staging row: wave covers rows 2wv,2wv+1
    int cg = lane & 31;                     // 32 lanes cover a row's 16B chunks
    int skg = cg & 3, skb = cg >> 2;

    // ---- scalar outputs (depend only on k_prep's xpart): one designated block ----
    if (blockIdx.x == GRID_F - 1) {
        float v = xpart[tid] + xpart[tid + 512] + xpart[tid + 1024] + xpart[tid + 1536];
        v += __shfl_xor(v, 1);  v += __shfl_xor(v, 2);  v += __shfl_xor(v, 4);
        v += __shfl_xor(v, 8);  v += __shfl_xor(v, 16); v += __shfl_xor(v, 32);
        if (lane == 0) sqs[wv] = v;
        __syncthreads();
        if (tid == 0) {
            float e = sqs[0] + sqs[1] + sqs[2] + sqs[3] + sqs[4] + sqs[5] + sqs[6] + sqs[7];
            out[BD] = 0.0f;
            out[BD + 1] = sqrtf(e);
        }
        __syncthreads();
    }

    for (int si = slot0; si < nsub; si += SLOTS) {
        const int* e = wsi + 32 + (xcd * MAXSUB + si) * 3;
        int cond = e[0], prow0 = e[1], end = e[2];

        // ---- stage x: gather 16 bf16 rows (contiguous 2KB each) -> fragment LDS ----
        {
            int pr = prow0 + sr;
            int orow = sidx[pr < end ? pr : (end - 1)];
            const char* xs = (const char*)xbf + (size_t)orow * 2048;
#pragma unroll
            for (int it = 0; it < 4; ++it) {
                int m = it * 32 + cg;       // 16B chunk within row
                bf16x8 v = *(const bf16x8*)(xs + m * 16);
                int ks = it * 8 + skb;
                *(bf16x8*)(ldsx + ks * 1024 + skg * 256 + ((sr ^ skb) * 16)) = v;
            }
        }
        __syncthreads();

        // ---- L1: wave wv computes h cols [wv*16,+16); batched weight loads ----
        const char* bA = (const char*)w1s + (size_t)cond * 262144 + wv * 32768 + lane * 16;
        f32x4 acc = {};
#pragma unroll 1
        for (int kb = 0; kb < 4; ++kb) {
            bf16x8 b0 = *(const bf16x8*)(bA + (kb * 8 + 0) * 1024);
            bf16x8 b1 = *(const bf16x8*)(bA + (kb * 8 + 1) * 1024);
            bf16x8 b2 = *(const bf16x8*)(bA + (kb * 8 + 2) * 1024);
            bf16x8 b3 = *(const bf16x8*)(bA + (kb * 8 + 3) * 1024);
            bf16x8 b4 = *(const bf16x8*)(bA + (kb * 8 + 4) * 1024);
            bf16x8 b5 = *(const bf16x8*)(bA + (kb * 8 + 5) * 1024);
            bf16x8 b6 = *(const bf16x8*)(bA + (kb * 8 + 6) * 1024);
            bf16x8 b7 = *(const bf16x8*)(bA + (kb * 8 + 7) * 1024);
#pragma unroll
            for (int j = 0; j < 8; ++j) {
                int ks = kb * 8 + j;
                bf16x8 x0 = *(const bf16x8*)(ldsx + ks * 1024 + kg * 256 + ((l15 ^ (ks & 7)) * 16));
                bf16x8 bj = j == 0 ? b0 : j == 1 ? b1 : j == 2 ? b2 : j == 3 ? b3
                          : j == 4 ? b4 : j == 5 ? b5 : j == 6 ? b6 : b7;
                acc = __builtin_amdgcn_mfma_f32_16x16x32_bf16(x0, bj, acc, 0, 0, 0);
            }
        }
        __syncthreads();   // all waves done reading x region

        // ---- h + b1 -> Hs (swizzled bf16) ----
        {
            int j0 = wv * 16 + l15;
            float bias = b1f[cond * 128 + j0];
            int sl0 = j0 >> 3, jb = j0 & 7;
#pragma unroll
            for (int v = 0; v < 4; ++v) {
                int r0 = kg * 4 + v;
                __bf16 h0 = (__bf16)(acc[v] + bias);
                Hs[r0 * 128 + ((sl0 ^ (r0 & 7)) * 8) + jb] = __builtin_bit_cast(ushort_t, h0);
            }
        }
        __syncthreads();

        // ---- pa fragments ----
        bf16x8 pa[4];
#pragma unroll
        for (int i = 0; i < 4; ++i)
            pa[i] = *(const bf16x8*)(Hs + l15 * 128 + (((i * 4 + kg) ^ (l15 & 7)) * 8));

        // ---- L2: wave wv owns out cols [wv*128,+128) ----
        const char* w2b = (const char*)w2s + (size_t)cond * 262144 + wv * 32768 + lane * 16;
        float sq[4] = {0.f, 0.f, 0.f, 0.f};
        unsigned cswz = (unsigned)((kg & 1) << 4);
#pragma unroll 1
        for (int f = 0; f < 8; ++f) {
            const char* wb = w2b + f * 4096;
            bf16x8 q0 = *(const bf16x8*)(wb);
            bf16x8 q1 = *(const bf16x8*)(wb + 1024);
            bf16x8 q2 = *(const bf16x8*)(wb + 2048);
            bf16x8 q3 = *(const bf16x8*)(wb + 3072);
            f32x4 c0 = {};
            c0 = __builtin_amdgcn_mfma_f32_16x16x32_bf16(pa[0], q0, c0, 0, 0, 0);
            c0 = __builtin_amdgcn_mfma_f32_16x16x32_bf16(pa[1], q1, c0, 0, 0, 0);
            c0 = __builtin_amdgcn_mfma_f32_16x16x32_bf16(pa[2], q2, c0, 0, 0, 0);
            c0 = __builtin_amdgcn_mfma_f32_16x16x32_bf16(pa[3], q3, c0, 0, 0, 0);
            int jg = (wv * 8 + f) * 16 + l15;
            float bias = b2f[cond * 1024 + jg];
            float t0 = c0[0] + bias, t1 = c0[1] + bias, t2 = c0[2] + bias, t3 = c0[3] + bias;
            sq[0] += t0*t0; sq[1] += t1*t1; sq[2] += t2*t2; sq[3] += t3*t3;
            unsigned jc = (unsigned)jg ^ cswz;
            Ot32[(kg * 2    ) * 1024 + jc] = pack2(t0, t1);
            Ot32[(kg * 2 + 1) * 1024 + jc] = pack2(t2, t3);
        }
        // per-row sums: shfl over l15 -> LDS across waves
#pragma unroll
        for (int v = 0; v < 4; ++v) {
            float s = sq[v];
            s += __shfl_xor(s, 1); s += __shfl_xor(s, 2);
            s += __shfl_xor(s, 4); s += __shfl_xor(s, 8);
            if (l15 == 0) sqs[(kg * 4 + v) * 8 + wv] = s;
        }
        __syncthreads();

        // ---- fused normalize + fully-coalesced store: wave wv -> rows [wv*2,+2) ----
#pragma unroll 1
        for (int rr = 0; rr < 2; ++rr) {
            int r = wv * 2 + rr;
            int pr = prow0 + r;
            if (pr < end) {
                int orow = sidx[pr];
                float s = sqs[r*8+0] + sqs[r*8+1] + sqs[r*8+2] + sqs[r*8+3]
                        + sqs[r*8+4] + sqs[r*8+5] + sqs[r*8+6] + sqs[r*8+7];
                float inv = 1.0f / (sqrtf(s) + 1e-10f);
                int hi = (r & 1) * 16;
                unsigned rswz = (unsigned)(((r >> 2) & 1) << 4);
                const unsigned* base = Ot32 + (r >> 1) * 1024;
                float4* go = (float4*)(out + (size_t)orow * D_);
#pragma unroll
                for (int it = 0; it < 4; ++it) {
                    unsigned cu = (unsigned)(lane * 4 + it * 256) ^ rswz;
                    uint4 u = *(const uint4*)(base + cu);
                    float4 v;
                    v.x = (float)__builtin_bit_cast(__bf16, (ushort_t)(u.x >> hi)) * inv;
                    v.y = (float)__builtin_bit_cast(__bf16, (ushort_t)(u.y >> hi)) * inv;
                    v.z = (float)__builtin_bit_cast(__bf16, (ushort_t)(u.z >> hi)) * inv;
                    v.w = (float)__builtin_bit_cast(__bf16, (ushort_t)(u.w >> hi)) * inv;
                    go[lane + it * 64] = v;
                }
            }
        }
        __syncthreads();   // protect LDS for next subtile
    }
}

extern "C" void kernel_launch(void* const* d_in, const int* in_sizes, int n_in,
                              void* d_out, int out_size, void* d_ws, size_t ws_size,
                              hipStream_t stream) {
    const float* x  = (const float*)d_in[0];
    const int*   c  = (const int*)d_in[1];
    const float* W1 = (const float*)d_in[2];
    const float* b1 = (const float*)d_in[3];
    const float* W2 = (const float*)d_in[4];
    const float* b2 = (const float*)d_in[5];
    float* out = (float*)d_out;
    char* ws = (char*)d_ws;
    int* wsi = (int*)ws;
    float* xpart = (float*)(ws + 131072);
    __bf16* w1s  = (__bf16*)(ws + 262144);
    __bf16* w2s  = (__bf16*)(ws + 4456448);
    __bf16* xbf  = (__bf16*)(ws + 8650752);

    k_prep<<<2305, 256, 0, stream>>>(W1, W2, c, x, w1s, w2s, xbf, wsi, xpart, out);
    k_f<<<GRID_F, 512, 0, stream>>>(xbf, w1s, w2s, b1, b2, wsi, xpart, out);
}